// Round 15
// baseline (45.452 us; speedup 1.0000x reference)
//
#include <hip/hip_runtime.h>
#include <hip/hip_bf16.h>

#define HIDDEN 64
#define BATCH 2048
#define SFULL 1024
#define SM1 1023
#define LN_CLAMP -23.025850929940457f  // ln(1e-10)
#define SP_PER 16                      // grid.y = 64 -> 64*16 = 1024 sp slots

typedef __bf16 bf16x8 __attribute__((ext_vector_type(8)));
typedef float  f32x4  __attribute__((ext_vector_type(4)));

// Fragment cache (16x16x32 shape, R5-verified layout): 19 units [64][16B].
//  u 0..3  : a1[mt]      (b1 folded at k=3)
//  u 4..11 : a2[mt][c]   (u = 4 + mt*2 + c)
//  u 12,13 : a3[c]
//  u 14..17: c2init[mt]  (f32x4)
//  u 18    : c3init      (f32x4, bout on g==0)
#define FRAG_UNITS 19

// Row permutation mapping MFMA D-layout rows to B-layout k-indices (16x16).
// Hardware-verified R2-R5 (absmax 0.0).
__device__ __forceinline__ int permrow(int rho) {
    return 32 * ((rho >> 4) >> 1) + 8 * ((rho >> 2) & 3) + 4 * ((rho >> 4) & 1) + (rho & 3);
}

// truncating bf16 pack of 2 f32 (RTZ) -- verified R9/R10
__device__ __forceinline__ unsigned pkt(float lo, float hi) {
    return __builtin_amdgcn_perm(__float_as_uint(hi), __float_as_uint(lo), 0x07060302u);
}
// packed relu on 2 bf16 (int16 max-with-0) -- verified R11/R12
typedef short s16x2 __attribute__((ext_vector_type(2)));
__device__ __forceinline__ unsigned rp(unsigned x) {
    s16x2 v = __builtin_bit_cast(s16x2, x);
    s16x2 z = {0, 0};
    v = __builtin_elementwise_max(v, z);
    return __builtin_bit_cast(unsigned, v);
}

// relu+pack: B-frag c from accs a=acc[2c], b=acc[2c+1] (R5-verified mapping
// hf[c][j] = acc[2c + (j>>2)][j&3])
__device__ __forceinline__ bf16x8 relu_pack2(const f32x4 a, const f32x4 b) {
    union { unsigned u[4]; bf16x8 v; } r;
    r.u[0] = rp(pkt(a[0], a[1]));
    r.u[1] = rp(pkt(a[2], a[3]));
    r.u[2] = rp(pkt(b[0], b[1]));
    r.u[3] = rp(pkt(b[2], b[3]));
    return r.v;
}

// feature B-frag {xt, t, x0, 1, ...}; only g==0 k=0..3 reach nonzero A rows
__device__ __forceinline__ bf16x8 featpk(float xt, float t, float x0) {
    union { unsigned u[4]; bf16x8 v; } r;
    r.u[0] = pkt(xt, t);
    r.u[1] = pkt(x0, 1.0f);
    r.u[2] = r.u[0]; r.u[3] = r.u[1];
    return r.v;
}

// ---------------- Kernel 0: one-time fragment gather (1 block) -------------
// Identical math to R5's verified setup.
__global__ __launch_bounds__(256) void frag_setup_kernel(
    const float* __restrict__ W1, const float* __restrict__ b1,
    const float* __restrict__ W2, const float* __restrict__ b2,
    const float* __restrict__ Wout, const float* __restrict__ bout,
    char* __restrict__ F)
{
    const int lane = threadIdx.x & 63;
    const int wv   = threadIdx.x >> 6;
    const int col  = lane & 15;
    const int g    = lane >> 4;

    if (wv == 0) {
        // a1 (bias folded into k=3) + a3 + c3init
#pragma unroll
        for (int mt = 0; mt < 4; ++mt) {
            const int p2 = permrow(16 * mt + col);
            bf16x8 v;
#pragma unroll
            for (int j = 0; j < 8; ++j) {
                const int k = 8 * g + j;
                v[j] = (k < 3) ? (__bf16)W1[k * 64 + p2]
                     : (k == 3) ? (__bf16)b1[p2] : (__bf16)0.0f;
            }
            *(bf16x8*)(F + ((mt * 64 + lane) << 4)) = v;
        }
#pragma unroll
        for (int c = 0; c < 2; ++c) {
            bf16x8 v;
#pragma unroll
            for (int j = 0; j < 8; ++j)
                v[j] = (col < 3) ? (__bf16)Wout[(32 * c + 8 * g + j) * 3 + col] : (__bf16)0.0f;
            *(bf16x8*)(F + (((12 + c) * 64 + lane) << 4)) = v;
        }
        f32x4 c3 = {0.f, 0.f, 0.f, 0.f};
        if (g == 0) { c3[0] = bout[0]; c3[1] = bout[1]; c3[2] = bout[2]; }
        *(f32x4*)(F + ((18 * 64 + lane) << 4)) = c3;
    } else if (wv == 1 || wv == 2) {
        // a2 for mt = {0,1} (wv 1) or {2,3} (wv 2)
#pragma unroll
        for (int m = 0; m < 2; ++m) {
            const int mt = (wv - 1) * 2 + m;
            const int p2 = permrow(16 * mt + col);
#pragma unroll
            for (int c = 0; c < 2; ++c) {
                bf16x8 v;
#pragma unroll
                for (int j = 0; j < 8; ++j)
                    v[j] = (__bf16)W2[(32 * c + 8 * g + j) * 64 + p2];
                *(bf16x8*)(F + (((4 + mt * 2 + c) * 64 + lane) << 4)) = v;
            }
        }
    } else {
        // c2init
#pragma unroll
        for (int mt = 0; mt < 4; ++mt) {
            f32x4 v;
#pragma unroll
            for (int r = 0; r < 4; ++r)
                v[r] = b2[permrow(16 * mt + 4 * g + r)];
            *(f32x4*)(F + (((14 + mt) * 64 + lane) << 4)) = v;
        }
    }
}

// ---------------- Kernel 1: 3-layer MLP, 16x16x32, frags in LDS ------------
// grid (32, 64), block 256 (4 waves), __launch_bounds__(256,4).
// Wave owns 16 points b = (blockIdx.x*4+wv)*16 + (lane&15); 16 sp iterations.
// Small f32x4 accumulators (peak AGPR ~24) + LDS-resident weight frags keep
// total regs <=128 -> 4 resident waves/SIMD (the occupancy lever).
// Per sp: L1 4 mfma -> pack -> L2 2x4 mfma (C=c2init) -> pack -> L3 2 mfma.
__global__ __launch_bounds__(256, 4) void mlp_z_kernel(
    const float* __restrict__ ys,    // (B, S, 2)
    const char* __restrict__ F,      // fragment cache (global)
    float* __restrict__ z)           // (SM1, BATCH)
{
    __shared__ __align__(16) char Flds[14 * 64 * 16];

    const int l    = threadIdx.x & 63;
    const int wv   = threadIdx.x >> 6;
    const int col  = l & 15;

    // stage F units 0..13 (a1, a2, a3) into LDS, coalesced
    for (int i = threadIdx.x; i < 14 * 64; i += 256)
        *(f32x4*)(Flds + ((size_t)i << 4)) = *(const f32x4*)(F + ((size_t)i << 4));

    const int b   = (blockIdx.x * 4 + wv) * 16 + col;
    const int sp0 = blockIdx.y * SP_PER;
    const int omax = (SFULL - 1) - sp0;

    // register-resident C-inits (f32x4 each)
    f32x4 c2init[4], c3init;
#pragma unroll
    for (int mt = 0; mt < 4; ++mt)
        c2init[mt] = *(const f32x4*)(F + (((14 + mt) * 64 + l) << 4));
    c3init = *(const f32x4*)(F + ((18 * 64 + l) << 4));

    const f32x4 zero4 = {0.f, 0.f, 0.f, 0.f};

    const float2* base2 = reinterpret_cast<const float2*>(ys) + ((size_t)b * SFULL + sp0);
    float* zb = z + (size_t)sp0 * BATCH + b;

    float2 q0 = base2[0];
    float2 q1 = base2[min(1, omax)];
    float2 qn = base2[min(2, omax)];

    __syncthreads();

    for (int it = 0; it < SP_PER; ++it) {
        // opaque offset: defeats LICM so LDS frags aren't hoisted to regs
        unsigned loff = (unsigned)(l << 4);
        asm volatile("" : "+v"(loff));
#define LDSF(u) (*(const bf16x8*)(Flds + ((u) * 1024) + loff))

        const float2 qn2 = base2[min(it + 3, omax)];  // prefetch

        const float x0 = q0.y, t = q1.x, xt = q1.y;
        const bf16x8 f0 = featpk(xt, t, x0);

        // ---- layer 1 (b1 folded) ----
        bf16x8 w10 = LDSF(0), w11 = LDSF(1), w12 = LDSF(2), w13 = LDSF(3);
        f32x4 acc1[4];
        acc1[0] = __builtin_amdgcn_mfma_f32_16x16x32_bf16(w10, f0, zero4, 0, 0, 0);
        acc1[1] = __builtin_amdgcn_mfma_f32_16x16x32_bf16(w11, f0, zero4, 0, 0, 0);
        acc1[2] = __builtin_amdgcn_mfma_f32_16x16x32_bf16(w12, f0, zero4, 0, 0, 0);
        acc1[3] = __builtin_amdgcn_mfma_f32_16x16x32_bf16(w13, f0, zero4, 0, 0, 0);

        // early reads for L2 first half (hide under L1 + pack)
        bf16x8 w200 = LDSF(4), w210 = LDSF(6), w220 = LDSF(8), w230 = LDSF(10);

        bf16x8 hf[2];
        hf[0] = relu_pack2(acc1[0], acc1[1]);
        hf[1] = relu_pack2(acc1[2], acc1[3]);

        // ---- layer 2 ----
        f32x4 acc2[4];
        acc2[0] = __builtin_amdgcn_mfma_f32_16x16x32_bf16(w200, hf[0], c2init[0], 0, 0, 0);
        acc2[1] = __builtin_amdgcn_mfma_f32_16x16x32_bf16(w210, hf[0], c2init[1], 0, 0, 0);
        acc2[2] = __builtin_amdgcn_mfma_f32_16x16x32_bf16(w220, hf[0], c2init[2], 0, 0, 0);
        acc2[3] = __builtin_amdgcn_mfma_f32_16x16x32_bf16(w230, hf[0], c2init[3], 0, 0, 0);

        bf16x8 w201 = LDSF(5), w211 = LDSF(7), w221 = LDSF(9), w231 = LDSF(11);
        acc2[0] = __builtin_amdgcn_mfma_f32_16x16x32_bf16(w201, hf[1], acc2[0], 0, 0, 0);
        acc2[1] = __builtin_amdgcn_mfma_f32_16x16x32_bf16(w211, hf[1], acc2[1], 0, 0, 0);
        acc2[2] = __builtin_amdgcn_mfma_f32_16x16x32_bf16(w221, hf[1], acc2[2], 0, 0, 0);
        acc2[3] = __builtin_amdgcn_mfma_f32_16x16x32_bf16(w231, hf[1], acc2[3], 0, 0, 0);

        // L3 weight reads (hide under L2 tail + pack)
        bf16x8 w30 = LDSF(12), w31 = LDSF(13);

        bf16x8 h2f[2];
        h2f[0] = relu_pack2(acc2[0], acc2[1]);
        h2f[1] = relu_pack2(acc2[2], acc2[3]);

        // ---- layer 3 ----
        f32x4 acc3;
        acc3 = __builtin_amdgcn_mfma_f32_16x16x32_bf16(w30, h2f[0], c3init, 0, 0, 0);
        acc3 = __builtin_amdgcn_mfma_f32_16x16x32_bf16(w31, h2f[1], acc3, 0, 0, 0);
#undef LDSF

        // Hermite (g==0 lanes hold c0,c1,c2 = acc3[0..2], bout folded)
        const float zv = fmaf(acc3[2], fmaf(4.0f * xt, xt, -2.0f),
                         fmaf(acc3[1], xt + xt, acc3[0]));

        if (l < 16 && sp0 + it < SM1)
            zb[(size_t)it * BATCH] = zv;

        q0 = q1; q1 = qn; qn = qn2;
    }
}

// ---------------- reduction helpers ----------------
__device__ __forceinline__ float blk_reduce_max(float v) {
    __shared__ float s[4];
#pragma unroll
    for (int off = 32; off >= 1; off >>= 1) v = fmaxf(v, __shfl_xor(v, off));
    if ((threadIdx.x & 63) == 0) s[threadIdx.x >> 6] = v;
    __syncthreads();
    v = fmaxf(fmaxf(s[0], s[1]), fmaxf(s[2], s[3]));
    __syncthreads();
    return v;
}

__device__ __forceinline__ float blk_reduce_sum(float v) {
    __shared__ float s[4];
#pragma unroll
    for (int off = 32; off >= 1; off >>= 1) v += __shfl_xor(v, off);
    if ((threadIdx.x & 63) == 0) s[threadIdx.x >> 6] = v;
    __syncthreads();
    v = (s[0] + s[1]) + (s[2] + s[3]);
    __syncthreads();
    return v;
}

// ---------------- Kernel 2: per-column softmax + logclip sum ----------------
__global__ __launch_bounds__(256) void col_softmax_kernel(
    const float* __restrict__ z, float* __restrict__ colsum)
{
    const int sp = blockIdx.x;
    const int tid = threadIdx.x;
    const float* col = z + (size_t)sp * BATCH;

    float vals[8];
    float m = -3.4e38f;
#pragma unroll
    for (int i = 0; i < 8; ++i) {
        vals[i] = col[tid + 256 * i];
        m = fmaxf(m, vals[i]);
    }
    const float M = blk_reduce_max(m);

    float se = 0.0f;
#pragma unroll
    for (int i = 0; i < 8; ++i) se += __expf(vals[i] - M);
    const float S = blk_reduce_sum(se);
    const float L = __logf(S);

    float acc = 0.0f;
#pragma unroll
    for (int i = 0; i < 8; ++i) acc += fmaxf(vals[i] - M - L, LN_CLAMP);
    const float T = blk_reduce_sum(acc);
    if (tid == 0) colsum[sp] = T;
}

// ---------------- Kernel 3: final scalar ----------------
__global__ __launch_bounds__(256) void final_reduce_kernel(
    const float* __restrict__ colsum, float* __restrict__ out)
{
    const int tid = threadIdx.x;
    float v = 0.0f;
    for (int i = tid; i < SM1; i += 256) v += colsum[i];
    const float T = blk_reduce_sum(v);
    if (tid == 0) out[0] = T / (float)BATCH;
}

extern "C" void kernel_launch(void* const* d_in, const int* in_sizes, int n_in,
                              void* d_out, int out_size, void* d_ws, size_t ws_size,
                              hipStream_t stream) {
    const float* ys   = (const float*)d_in[0];
    const float* W1   = (const float*)d_in[1];
    const float* b1   = (const float*)d_in[2];
    const float* W2   = (const float*)d_in[3];
    const float* b2   = (const float*)d_in[4];
    const float* Wout = (const float*)d_in[5];
    const float* bout = (const float*)d_in[6];
    float* out = (float*)d_out;

    float* z      = (float*)d_ws;                         // SM1*BATCH floats
    float* colsum = z + (size_t)SM1 * BATCH;              // SM1 floats
    size_t fo = ((size_t)SM1 * BATCH + SM1) * sizeof(float);
    fo = (fo + 15) & ~(size_t)15;
    char* F = (char*)d_ws + fo;                           // 19*64*16 = 19 KB

    frag_setup_kernel<<<1, 256, 0, stream>>>(W1, b1, W2, b2, Wout, bout, F);
    dim3 grid1(32, 64);  // 32*4 waves * 16 pts = 2048 b ; 64*16 = 1024 sp slots
    mlp_z_kernel<<<grid1, 256, 0, stream>>>(ys, F, z);
    col_softmax_kernel<<<SM1, 256, 0, stream>>>(z, colsum);
    final_reduce_kernel<<<1, 256, 0, stream>>>(colsum, out);
}

// Round 16
// 43.113 us; speedup vs baseline: 1.0542x; 1.0542x over previous
//
#include <hip/hip_runtime.h>
#include <hip/hip_bf16.h>

#define HIDDEN 64
#define BATCH 2048
#define SFULL 1024
#define SM1 1023
#define LN_CLAMP -23.025850929940457f  // ln(1e-10)
#define PAIRS 8                        // 16 sp per block (grid.y = 64)

typedef __bf16 bf16x8 __attribute__((ext_vector_type(8)));
typedef float  f32x4  __attribute__((ext_vector_type(4)));
typedef float  f32x16 __attribute__((ext_vector_type(16)));
typedef short  s16x2  __attribute__((ext_vector_type(2)));

// Global fragment cache: 16 units of [64 lanes][16B] (R11-verified layout).
//  u 0,1   : a1[mt]     (registers)
//  u 2..9  : a2[mt][c]  -> LDS unit mt*4+c
//  u 10..13: a3[c]      -> LDS unit 8+c
//  u 14,15 : a2b[mt]    -> LDS unit 12+mt
#define FRAG_UNITS 16

// sigma mapping (hardware-verified R7-R14, absmax 0.0)
__device__ __forceinline__ int sig(int rg) {
    return 16 * ((rg >> 3) & 3) + 8 * ((rg >> 2) & 1) + (rg & 3) + 4 * (rg >> 5);
}

// truncating bf16 pack (RTZ) -- verified R9+
__device__ __forceinline__ unsigned pkt(float lo, float hi) {
    return __builtin_amdgcn_perm(__float_as_uint(hi), __float_as_uint(lo), 0x07060302u);
}
// packed relu on 2 bf16 -- verified R11+
__device__ __forceinline__ unsigned rp(unsigned x) {
    s16x2 v = __builtin_bit_cast(s16x2, x);
    s16x2 z = {0, 0};
    v = __builtin_elementwise_max(v, z);
    return __builtin_bit_cast(unsigned, v);
}

// pack+relu two f32x16 D-frags into 4 B-frags (layout verified R7)
__device__ __forceinline__ void relu_pack4(const f32x16 lo, const f32x16 hi, bf16x8* out) {
#pragma unroll
    for (int c = 0; c < 4; ++c) {
        union { unsigned u[4]; bf16x8 v; } r;
        r.u[0] = rp(pkt(lo[4 * c + 0], lo[4 * c + 1]));
        r.u[1] = rp(pkt(lo[4 * c + 2], lo[4 * c + 3]));
        r.u[2] = rp(pkt(hi[4 * c + 0], hi[4 * c + 1]));
        r.u[3] = rp(pkt(hi[4 * c + 2], hi[4 * c + 3]));
        out[c] = r.v;
    }
}

// feature B-frag {xt, t, x0, 1, ...}
__device__ __forceinline__ bf16x8 featpk(float xt, float t, float x0) {
    union { unsigned u[4]; bf16x8 v; } r;
    r.u[0] = pkt(xt, t);
    r.u[1] = pkt(x0, 1.0f);
    r.u[2] = r.u[0]; r.u[3] = r.u[1];
    return r.v;
}

// ---------------- Kernel 0: one-time fragment gather (1 block) -------------
__global__ __launch_bounds__(256) void frag_setup_kernel(
    const float* __restrict__ W1, const float* __restrict__ b1,
    const float* __restrict__ W2, const float* __restrict__ b2,
    const float* __restrict__ Wout, char* __restrict__ F)
{
    const int l    = threadIdx.x & 63;
    const int wv   = threadIdx.x >> 6;
    const int pcol = l & 31;
    const int hi   = l >> 5;

    if (wv == 0) {
#pragma unroll
        for (int mt = 0; mt < 2; ++mt) {
            const int hout = sig(32 * mt + pcol);
            bf16x8 v;
#pragma unroll
            for (int j = 0; j < 8; ++j) {
                const int k = 8 * hi + j;
                v[j] = (k < 3) ? (__bf16)W1[k * 64 + hout]
                     : (k == 3) ? (__bf16)b1[hout] : (__bf16)0.0f;
            }
            *(bf16x8*)(F + ((mt * 64 + l) << 4)) = v;
        }
#pragma unroll
        for (int c = 0; c < 4; ++c) {
            bf16x8 v;
#pragma unroll
            for (int j = 0; j < 8; ++j) {
                const int k = 16 * c + 8 * hi + j;
                v[j] = (pcol < 3) ? (__bf16)Wout[k * 3 + pcol] : (__bf16)0.0f;
            }
            *(bf16x8*)(F + (((10 + c) * 64 + l) << 4)) = v;
        }
    } else if (wv == 1 || wv == 2) {
        const int mt = wv - 1;
        const int hout = sig(32 * mt + pcol);
#pragma unroll
        for (int c = 0; c < 4; ++c) {
            bf16x8 v;
#pragma unroll
            for (int j = 0; j < 8; ++j)
                v[j] = (__bf16)W2[(16 * c + 8 * hi + j) * 64 + hout];
            *(bf16x8*)(F + (((2 + mt * 4 + c) * 64 + l) << 4)) = v;
        }
    } else {
#pragma unroll
        for (int mt = 0; mt < 2; ++mt) {
            const int hout = sig(32 * mt + pcol);
            bf16x8 v;
#pragma unroll
            for (int j = 0; j < 8; ++j)
                v[j] = (hi == 0 && j == 0) ? (__bf16)b2[hout] : (__bf16)0.0f;
            *(bf16x8*)(F + (((14 + mt) * 64 + l) << 4)) = v;
        }
    }
}

// ---------------- Kernel 1: pipelined 3-layer MLP (ping-pong L1) -----------
// grid (16, 64), block 256 (4 waves). Wave owns 32 points; 8 outer iters x
// 2 sp. L1 of sp+1 is issued BEFORE consuming sp's L1 result (computed one
// phase earlier) -> in-phase critical path is pack->L2->pack->L3 only, and
// the L1-next + bias MFMAs fill the pack bubbles on the matrix pipe.
__global__ __launch_bounds__(256, 2) void mlp_z_kernel(
    const float* __restrict__ ys,    // (B, S, 2)
    const char* __restrict__ F,      // fragment cache (global)
    const float* __restrict__ bout,  // (3)
    float* __restrict__ z)           // (SM1, BATCH)
{
    __shared__ __align__(16) char Flds[14 * 64 * 16];

    const int l    = threadIdx.x & 63;
    const int wv   = threadIdx.x >> 6;
    const int pcol = l & 31;
    const int hi   = l >> 5;

    for (int i = threadIdx.x; i < 14 * 64; i += 256)
        *(f32x4*)(Flds + ((size_t)i << 4)) =
            *(const f32x4*)(F + ((size_t)(2 * 64 + i) << 4));

    const int b   = (blockIdx.x * 4 + wv) * 32 + pcol;
    const int sp0 = blockIdx.y * (2 * PAIRS);
    const int omax = (SFULL - 1) - sp0;

    bf16x8 a1r[2];
    a1r[0] = *(const bf16x8*)(F + ((0 * 64 + l) << 4));
    a1r[1] = *(const bf16x8*)(F + ((1 * 64 + l) << 4));

    bf16x8 Bone;
    {
        union { unsigned u[4]; bf16x8 v; } r;
        r.u[0] = (hi == 0) ? 0x3F80u : 0u;  // bf16(1.0)
        r.u[1] = 0u; r.u[2] = 0u; r.u[3] = 0u;
        Bone = r.v;
    }

    const float bo0 = bout[0], bo1 = bout[1], bo2 = bout[2];

    f32x16 zero16;
#pragma unroll
    for (int i = 0; i < 16; ++i) zero16[i] = 0.0f;

    const float2* base2 = reinterpret_cast<const float2*>(ys) + ((size_t)b * SFULL + sp0);
    float* zb = z + (size_t)sp0 * BATCH + b;

    float2 qa = base2[0];
    float2 qb = base2[min(1, omax)];
    float2 qc = base2[min(2, omax)];

    __syncthreads();

    // prologue: L1 for sp0+0
    f32x16 accP_0, accP_1, accQ_0, accQ_1;
    {
        const bf16x8 f0 = featpk(qb.y, qb.x, qa.y);
        accP_0 = __builtin_amdgcn_mfma_f32_32x32x16_bf16(a1r[0], f0, zero16, 0, 0, 0);
        accP_1 = __builtin_amdgcn_mfma_f32_32x32x16_bf16(a1r[1], f0, zero16, 0, 0, 0);
    }

#define LDSF(u) (*(const bf16x8*)(Flds + ((u) * 1024) + loff))
#define BODY(ACC0, ACC1, NACC0, NACC1, XTCUR, F0NEXT, STORE_GUARD, ZOFF)        \
    {                                                                           \
        unsigned loff = (unsigned)(l << 4);                                     \
        asm volatile("" : "+v"(loff));                                          \
        /* L1 for NEXT sp (independent -> fills matrix pipe) */                 \
        NACC0 = __builtin_amdgcn_mfma_f32_32x32x16_bf16(a1r[0], F0NEXT, zero16, 0, 0, 0); \
        NACC1 = __builtin_amdgcn_mfma_f32_32x32x16_bf16(a1r[1], F0NEXT, zero16, 0, 0, 0); \
        /* bias MFMAs start L2 accumulators (independent) */                    \
        bf16x8 wb0 = LDSF(12), wb1 = LDSF(13);                                  \
        f32x16 acc2_0 = __builtin_amdgcn_mfma_f32_32x32x16_bf16(wb0, Bone, zero16, 0, 0, 0); \
        f32x16 acc2_1 = __builtin_amdgcn_mfma_f32_32x32x16_bf16(wb1, Bone, zero16, 0, 0, 0); \
        bf16x8 w2_0 = LDSF(0), w2_1 = LDSF(4);                                  \
        /* pack current h1 (ACC ready since previous phase) */                  \
        bf16x8 h1f[4];                                                          \
        relu_pack4(ACC0, ACC1, h1f);                                            \
        _Pragma("unroll")                                                       \
        for (int c = 0; c < 4; ++c) {                                           \
            bf16x8 n0, n1;                                                      \
            if (c < 3) { n0 = LDSF(c + 1); n1 = LDSF(4 + c + 1); }              \
            acc2_0 = __builtin_amdgcn_mfma_f32_32x32x16_bf16(w2_0, h1f[c], acc2_0, 0, 0, 0); \
            acc2_1 = __builtin_amdgcn_mfma_f32_32x32x16_bf16(w2_1, h1f[c], acc2_1, 0, 0, 0); \
            if (c < 3) { w2_0 = n0; w2_1 = n1; }                                \
        }                                                                       \
        bf16x8 h2f[4];                                                          \
        relu_pack4(acc2_0, acc2_1, h2f);                                        \
        bf16x8 w30 = LDSF(8), w31 = LDSF(9), w32 = LDSF(10), w33 = LDSF(11);    \
        /* L3: two parallel 2-chains (R8-verified) */                           \
        f32x16 acc3a = __builtin_amdgcn_mfma_f32_32x32x16_bf16(w30, h2f[0], zero16, 0, 0, 0); \
        f32x16 acc3b = __builtin_amdgcn_mfma_f32_32x32x16_bf16(w32, h2f[2], zero16, 0, 0, 0); \
        acc3a = __builtin_amdgcn_mfma_f32_32x32x16_bf16(w31, h2f[1], acc3a, 0, 0, 0); \
        acc3b = __builtin_amdgcn_mfma_f32_32x32x16_bf16(w33, h2f[3], acc3b, 0, 0, 0); \
        const float c0 = acc3a[0] + acc3b[0] + bo0;                             \
        const float c1 = acc3a[1] + acc3b[1] + bo1;                             \
        const float c2 = acc3a[2] + acc3b[2] + bo2;                             \
        const float xt_ = (XTCUR);                                              \
        const float zv = fmaf(c2, fmaf(4.0f * xt_, xt_, -2.0f),                 \
                         fmaf(c1, xt_ + xt_, c0));                              \
        if (l < 32 && (STORE_GUARD)) zb[(size_t)(ZOFF) * BATCH] = zv;           \
    }

    for (int it = 0; it < PAIRS; ++it) {
        // phase A: consume accP (sp = sp0+2it); produce accQ (sp+1)
        const bf16x8 f0b = featpk(qc.y, qc.x, qb.y);        // feats(sp+1)
        const float2 nb = base2[min(2 * it + 3, omax)];
        BODY(accP_0, accP_1, accQ_0, accQ_1, qb.y, f0b, true, 2 * it)

        // phase B: consume accQ (sp+1); produce accP (sp+2)
        const bf16x8 f0c = featpk(nb.y, nb.x, qc.y);        // feats(sp+2)
        const float2 nc = base2[min(2 * it + 4, omax)];
        BODY(accQ_0, accQ_1, accP_0, accP_1, qc.y, f0c,
             (sp0 + 2 * it + 1 < SM1), 2 * it + 1)

        qa = qc; qb = nb; qc = nc;
    }
#undef BODY
#undef LDSF
}

// ---------------- reduction helpers ----------------
__device__ __forceinline__ float blk_reduce_max(float v) {
    __shared__ float s[4];
#pragma unroll
    for (int off = 32; off >= 1; off >>= 1) v = fmaxf(v, __shfl_xor(v, off));
    if ((threadIdx.x & 63) == 0) s[threadIdx.x >> 6] = v;
    __syncthreads();
    v = fmaxf(fmaxf(s[0], s[1]), fmaxf(s[2], s[3]));
    __syncthreads();
    return v;
}

__device__ __forceinline__ float blk_reduce_sum(float v) {
    __shared__ float s[4];
#pragma unroll
    for (int off = 32; off >= 1; off >>= 1) v += __shfl_xor(v, off);
    if ((threadIdx.x & 63) == 0) s[threadIdx.x >> 6] = v;
    __syncthreads();
    v = (s[0] + s[1]) + (s[2] + s[3]);
    __syncthreads();
    return v;
}

// ---------------- Kernel 2: per-column softmax + logclip sum ----------------
__global__ __launch_bounds__(256) void col_softmax_kernel(
    const float* __restrict__ z, float* __restrict__ colsum)
{
    const int sp = blockIdx.x;
    const int tid = threadIdx.x;
    const float* col = z + (size_t)sp * BATCH;

    float vals[8];
    float m = -3.4e38f;
#pragma unroll
    for (int i = 0; i < 8; ++i) {
        vals[i] = col[tid + 256 * i];
        m = fmaxf(m, vals[i]);
    }
    const float M = blk_reduce_max(m);

    float se = 0.0f;
#pragma unroll
    for (int i = 0; i < 8; ++i) se += __expf(vals[i] - M);
    const float S = blk_reduce_sum(se);
    const float L = __logf(S);

    float acc = 0.0f;
#pragma unroll
    for (int i = 0; i < 8; ++i) acc += fmaxf(vals[i] - M - L, LN_CLAMP);
    const float T = blk_reduce_sum(acc);
    if (tid == 0) colsum[sp] = T;
}

// ---------------- Kernel 3: final scalar ----------------
__global__ __launch_bounds__(256) void final_reduce_kernel(
    const float* __restrict__ colsum, float* __restrict__ out)
{
    const int tid = threadIdx.x;
    float v = 0.0f;
    for (int i = tid; i < SM1; i += 256) v += colsum[i];
    const float T = blk_reduce_sum(v);
    if (tid == 0) out[0] = T / (float)BATCH;
}

extern "C" void kernel_launch(void* const* d_in, const int* in_sizes, int n_in,
                              void* d_out, int out_size, void* d_ws, size_t ws_size,
                              hipStream_t stream) {
    const float* ys   = (const float*)d_in[0];
    const float* W1   = (const float*)d_in[1];
    const float* b1   = (const float*)d_in[2];
    const float* W2   = (const float*)d_in[3];
    const float* b2   = (const float*)d_in[4];
    const float* Wout = (const float*)d_in[5];
    const float* bout = (const float*)d_in[6];
    float* out = (float*)d_out;

    float* z      = (float*)d_ws;                         // SM1*BATCH floats
    float* colsum = z + (size_t)SM1 * BATCH;              // SM1 floats
    size_t fo = ((size_t)SM1 * BATCH + SM1) * sizeof(float);
    fo = (fo + 15) & ~(size_t)15;
    char* F = (char*)d_ws + fo;                           // 16*64*16 = 16 KB

    frag_setup_kernel<<<1, 256, 0, stream>>>(W1, b1, W2, b2, Wout, F);
    dim3 grid1(16, 64);  // 16*4 waves * 32 pts = 2048 b ; 64*16 = 1024 sp slots
    mlp_z_kernel<<<grid1, 256, 0, stream>>>(ys, F, bout, z);
    col_softmax_kernel<<<SM1, 256, 0, stream>>>(z, colsum);
    final_reduce_kernel<<<1, 256, 0, stream>>>(colsum, out);
}